// Round 1
// baseline (819.302 us; speedup 1.0000x reference)
//
#include <hip/hip_runtime.h>
#include <hip/hip_bf16.h>

// B=32, S=256, E=32, D=32. ALL DEVICE BUFFERS FP32 (reference dtypes).
// x = seq.reshape(32, 8192); Q/K/V = x @ W^T + b   (W: [8192,8192] row-major)
// attn = exp(QK^T)/(rowsum+1e-5) [no max-sub]; out = (attn @ V)/sqrt(32)
//
// GEMM strategy: HBM-bound on 805 MB of fp32 W. bf16 MFMA hi/lo split
// (3 of 4 product terms) for fp32-level accuracy at MFMA speed.
// THIS ROUND: split-K x4 (latency-bound fix). 295us qkv showed 17% occupancy
// / 17% HBM: not enough loads in flight. 6144 wave-tiles (24 waves/CU) with
// fp32 atomicAdd combine; bias pre-init folded into split_x.

#define FIN  8192
#define FOUT 8192
#define SD   8192
#define KSPLIT 4
#define KCHUNK 2048   // FIN / KSPLIT

typedef __attribute__((ext_vector_type(8))) short bf16x8;   // 8 bf16 (4 VGPRs)
typedef __attribute__((ext_vector_type(4))) float f32x4;
typedef __attribute__((ext_vector_type(4))) short short4v;

static __device__ __forceinline__ short bf16_hi(float w, float& hf) {
    __hip_bfloat16 h = __float2bfloat16(w);      // RNE
    hf = __bfloat162float(h);
    return *(short*)&h;
}
static __device__ __forceinline__ short bf16_of(float w) {
    __hip_bfloat16 h = __float2bfloat16(w);
    return *(short*)&h;
}

// ---------------------------------------------------------------------------
// Kernel 0: split fp32 x -> bf16 hi + bf16 lo (65536 float4), AND pre-init
// Q/K/V with broadcast bias rows (65536 float4 each) so the split-K GEMM can
// atomicAdd partials directly.
// ---------------------------------------------------------------------------
__global__ __launch_bounds__(256) void split_x_init(
    const float* __restrict__ x, short* __restrict__ xh, short* __restrict__ xl,
    const float* __restrict__ bq, const float* __restrict__ bk,
    const float* __restrict__ bv,
    float* __restrict__ Qf, float* __restrict__ Kf, float* __restrict__ Vf)
{
    const int i = blockIdx.x * 256 + threadIdx.x;      // float4 index
    float4 v = ((const float4*)x)[i];
    float wf[4] = {v.x, v.y, v.z, v.w};
    short h[4], l[4];
    #pragma unroll
    for (int j = 0; j < 4; ++j) {
        float hf;
        h[j] = bf16_hi(wf[j], hf);
        l[j] = bf16_of(wf[j] - hf);                    // wf-hf exact (Sterbenz)
    }
    ((short4v*)xh)[i] = short4v{h[0], h[1], h[2], h[3]};
    ((short4v*)xl)[i] = short4v{l[0], l[1], l[2], l[3]};

    // bias init: [32][8192] fp32 = 65536 float4 per matrix; i covers exactly one
    const int col4 = i & 2047;                         // float4 col within row
    ((float4*)Qf)[i] = ((const float4*)bq)[col4];
    ((float4*)Kf)[i] = ((const float4*)bk)[col4];
    ((float4*)Vf)[i] = ((const float4*)bv)[col4];
}

// ---------------------------------------------------------------------------
// Kernel 1: fused QKV GEMM, split-K x4.
// 3072 blocks x 128 thr (2 waves) = 6144 wave-tiles
//   = 3 matrices x 512 n-tiles(16) x 4 k-chunks(2048).
// 12 blocks/CU -> 24 waves/CU (was 6): 4x loads in flight, HBM-latency fix.
// Wave: C[32 x 16] partial over its K-chunk, atomicAdd into bias-primed out.
// ---------------------------------------------------------------------------
__global__ __launch_bounds__(128, 6) void qkv_gemm(
    const short* __restrict__ xh, const short* __restrict__ xl,
    const float* __restrict__ Wq, const float* __restrict__ Wk,
    const float* __restrict__ Wv,
    float* __restrict__ outQ, float* __restrict__ outK, float* __restrict__ outV)
{
    const int wave = threadIdx.x >> 6;
    const int lane = threadIdx.x & 63;
    const int quad = lane >> 4;          // 0..3 -> k-octet
    const int r16  = lane & 15;

    const int tile  = blockIdx.x * 2 + wave;   // 0..6143
    const int which = tile >> 11;              // 0=Q 1=K 2=V   (2048 tiles each)
    const int rem   = tile & 2047;
    const int kc    = rem >> 9;                // 0..3  (slow: spreads atomic peers)
    const int nt    = rem & 511;               // 0..511

    const float* W; float* out;
    if (which == 0)      { W = Wq; out = outQ; }
    else if (which == 1) { W = Wk; out = outK; }
    else                 { W = Wv; out = outV; }

    const int n = nt * 16 + r16;               // owned W row / output column

    // A-frag layout (m89/m120): A[m=lane&15][k=quad*8+j]; chunk offset in
    // bf16x8 units = kc*2048/8 = kc*256.
    const int aoff = kc * 256;
    const bf16x8* Ah0 = (const bf16x8*)(xh + (size_t)r16        * FIN) + aoff;
    const bf16x8* Ah1 = (const bf16x8*)(xh + (size_t)(16 + r16) * FIN) + aoff;
    const bf16x8* Al0 = (const bf16x8*)(xl + (size_t)r16        * FIN) + aoff;
    const bf16x8* Al1 = (const bf16x8*)(xl + (size_t)(16 + r16) * FIN) + aoff;
    const float4* Wr  = (const float4*)(W + (size_t)n * FIN + (size_t)kc * KCHUNK);

    f32x4 acc0 = {0.f, 0.f, 0.f, 0.f};
    f32x4 acc1 = {0.f, 0.f, 0.f, 0.f};

    #pragma unroll 4
    for (int i = 0; i < KCHUNK / 32; ++i) {    // 64 iters
        const int idx = i * 4 + quad;          // bf16x8 units (16B); float4 = idx*2
        bf16x8 ah0 = Ah0[idx];
        bf16x8 ah1 = Ah1[idx];
        bf16x8 al0 = Al0[idx];
        bf16x8 al1 = Al1[idx];
        float4 w0 = Wr[idx * 2];
        float4 w1 = Wr[idx * 2 + 1];

        float wf[8] = {w0.x, w0.y, w0.z, w0.w, w1.x, w1.y, w1.z, w1.w};
        short hb[8], lb[8];
        #pragma unroll
        for (int j = 0; j < 8; ++j) {
            float hf;
            hb[j] = bf16_hi(wf[j], hf);
            lb[j] = bf16_of(wf[j] - hf);
        }
        bf16x8 wh = {hb[0],hb[1],hb[2],hb[3],hb[4],hb[5],hb[6],hb[7]};
        bf16x8 wl = {lb[0],lb[1],lb[2],lb[3],lb[4],lb[5],lb[6],lb[7]};

        acc0 = __builtin_amdgcn_mfma_f32_16x16x32_bf16(ah0, wh, acc0, 0, 0, 0);
        acc0 = __builtin_amdgcn_mfma_f32_16x16x32_bf16(al0, wh, acc0, 0, 0, 0);
        acc0 = __builtin_amdgcn_mfma_f32_16x16x32_bf16(ah0, wl, acc0, 0, 0, 0);
        acc1 = __builtin_amdgcn_mfma_f32_16x16x32_bf16(ah1, wh, acc1, 0, 0, 0);
        acc1 = __builtin_amdgcn_mfma_f32_16x16x32_bf16(al1, wh, acc1, 0, 0, 0);
        acc1 = __builtin_amdgcn_mfma_f32_16x16x32_bf16(ah1, wl, acc1, 0, 0, 0);
    }

    // C/D layout (m89): col = lane&15 (=n), row = quad*4 + reg.
    // Combine split-K partials with device-scope fp32 atomics (out is
    // bias-primed by split_x_init). 8 atomics/lane, peers spread by kc-major.
    #pragma unroll
    for (int i = 0; i < 4; ++i) {
        const int m = quad * 4 + i;
        atomicAdd(&out[(size_t)m        * FOUT + n], acc0[i]);
        atomicAdd(&out[(size_t)(m + 16) * FOUT + n], acc1[i]);
    }
}

// ---------------------------------------------------------------------------
// Kernel 2: attention, fp32, single pass (no max subtraction — faithful).
// grid = 32 batches x 8 row-tiles(32) = 256 blocks, 256 thr.
// ---------------------------------------------------------------------------
__global__ __launch_bounds__(256) void attention(
    const float* __restrict__ Qf, const float* __restrict__ Kf,
    const float* __restrict__ Vf, float* __restrict__ out)
{
    __shared__ float smem[16384];           // 64 KB: Ks | Vs, reused for partials
    float* Ks = smem;
    float* Vs = smem + SD;

    const int b     = blockIdx.x >> 3;
    const int stile = blockIdx.x & 7;
    const int tid   = threadIdx.x;

    const float* Kb = Kf + (size_t)b * SD;
    const float* Vb = Vf + (size_t)b * SD;
    for (int i = tid; i < SD / 4; i += 256) {
        ((float4*)Ks)[i] = ((const float4*)Kb)[i];
        ((float4*)Vs)[i] = ((const float4*)Vb)[i];
    }
    __syncthreads();

    const int srow  = tid & 31;
    const int chunk = tid >> 5;             // 0..7, each covers 32 t's
    const int s     = stile * 32 + srow;

    float q[32];
    const float* Qrow = Qf + (size_t)b * SD + (size_t)s * 32;
    #pragma unroll
    for (int d = 0; d < 32; ++d) q[d] = Qrow[d];

    float z[32];
    #pragma unroll
    for (int d = 0; d < 32; ++d) z[d] = 0.f;
    float den = 0.f;

    const int t0 = chunk * 32;
    for (int t = t0; t < t0 + 32; ++t) {
        const float* krow = Ks + t * 32;
        float scr = 0.f;
        #pragma unroll
        for (int d = 0; d < 32; ++d) scr += q[d] * krow[d];
        const float e = __expf(scr);
        den += e;
        const float* vrow = Vs + t * 32;
        #pragma unroll
        for (int d = 0; d < 32; ++d) z[d] += e * vrow[d];
    }

    __syncthreads();                        // done reading Ks/Vs
    float* pz   = smem;                     // [32][8][32]
    float* pden = smem + 8192;              // [32][8]
    #pragma unroll
    for (int d = 0; d < 32; ++d) pz[(srow * 8 + chunk) * 32 + d] = z[d];
    pden[srow * 8 + chunk] = den;
    __syncthreads();

    const int row = tid >> 3;               // 0..31
    const int dq  = tid & 7;                // 0..7
    float dsum = 0.f;
    #pragma unroll
    for (int c = 0; c < 8; ++c) dsum += pden[row * 8 + c];
    const float inv = 0.17677669529663687f / (dsum + 1e-5f);  // (1/sqrt(32))/(den+eps)

    const int so = stile * 32 + row;
    float* orow = out + (size_t)b * SD + (size_t)so * 32 + dq * 4;
    #pragma unroll
    for (int j = 0; j < 4; ++j) {
        float zz = 0.f;
        #pragma unroll
        for (int c = 0; c < 8; ++c) zz += pz[(row * 8 + c) * 32 + dq * 4 + j];
        orow[j] = zz * inv;
    }
}

// ---------------------------------------------------------------------------
extern "C" void kernel_launch(void* const* d_in, const int* in_sizes, int n_in,
                              void* d_out, int out_size, void* d_ws, size_t ws_size,
                              hipStream_t stream)
{
    const float* x  = (const float*)d_in[0];
    const float* Wq = (const float*)d_in[1];
    const float* bq = (const float*)d_in[2];
    const float* Wk = (const float*)d_in[3];
    const float* bk = (const float*)d_in[4];
    const float* Wv = (const float*)d_in[5];
    const float* bv = (const float*)d_in[6];
    float* out = (float*)d_out;

    // ws: xh[512KB] | xl[512KB] | Qf[1MB] | Kf[1MB] | Vf[1MB]  = 4 MB
    short* xh = (short*)d_ws;
    short* xl = xh + 262144;
    float* Qf = (float*)((char*)d_ws + (1u << 20));
    float* Kf = Qf + 262144;
    float* Vf = Kf + 262144;

    split_x_init<<<256, 256, 0, stream>>>(x, xh, xl, bq, bk, bv, Qf, Kf, Vf);
    qkv_gemm   <<<3072, 128, 0, stream>>>(xh, xl, Wq, Wk, Wv, Qf, Kf, Vf);
    attention  <<<256, 256, 0, stream>>>(Qf, Kf, Vf, out);
}

// Round 2
// 687.936 us; speedup vs baseline: 1.1910x; 1.1910x over previous
//
#include <hip/hip_runtime.h>
#include <hip/hip_bf16.h>

// B=32, S=256, E=32, D=32. ALL DEVICE BUFFERS FP32 (reference dtypes).
// x = seq.reshape(32, 8192); Q/K/V = x @ W^T + b   (W: [8192,8192] row-major)
// attn = exp(QK^T)/(rowsum+1e-5) [no max-sub]; out = (attn @ V)/sqrt(32)
//
// ROUND 2: BW was flat (1.3 TB/s) vs occupancy 17->50% => request-rate bound,
// not latency. Old W loads: 16B/lane scattered across 16 rows 32KB apart
// (channel-aliased, line-fragmented). Fix = canonical staging:
//   - W tiles [64][128] fp32 -> LDS via global_load_lds (contiguous 512B runs
//     per row), read-side XOR swizzle (row&7)<<4 with inverse-swizzled global
//     source (rule 21: linear dest + pre-swizzled src + swizzled read).
//   - x pre-swizzled into MFMA fragment order by split kernel => A loads are
//     wave-contiguous 1KB L2 broadcasts.
// Accuracy: bf16 hi/lo 3-term scheme unchanged.

#define FIN  8192
#define FOUT 8192
#define SD   8192
#define KSPLIT 2
#define KCHUNK 4096   // FIN / KSPLIT
#define BK 128        // floats staged per row per step
#define NT 64         // W rows per block tile

typedef __attribute__((ext_vector_type(8))) short bf16x8;   // 8 bf16 (4 VGPRs)
typedef __attribute__((ext_vector_type(4))) float f32x4;

static __device__ __forceinline__ short bf16_hi(float w, float& hf) {
    __hip_bfloat16 h = __float2bfloat16(w);      // RNE
    hf = __bfloat162float(h);
    return *(short*)&h;
}
static __device__ __forceinline__ short bf16_of(float w) {
    __hip_bfloat16 h = __float2bfloat16(w);
    return *(short*)&h;
}

static __device__ __forceinline__ void gload_lds16(const float* g, float* l) {
    __builtin_amdgcn_global_load_lds(
        (const __attribute__((address_space(1))) float*)g,
        (__attribute__((address_space(3))) float*)l, 16, 0, 0);
}

// ---------------------------------------------------------------------------
// Kernel 0: split fp32 x -> bf16 hi/lo, written PRE-SWIZZLED in MFMA fragment
// order: buffer[rb][i_step][lane][8] with lane=(quad<<4)|r16 holding
// x[rb*16+r16][i*32+quad*8 .. +8]. GEMM A-load = 1KB wave-contiguous.
// Also bias-primes Q/K/V (65536 float4 each) for split-K atomic combine.
// ---------------------------------------------------------------------------
__global__ __launch_bounds__(256) void split_x_init(
    const float* __restrict__ x,
    short* __restrict__ xh0, short* __restrict__ xh1,
    short* __restrict__ xl0, short* __restrict__ xl1,
    const float* __restrict__ bq, const float* __restrict__ bk,
    const float* __restrict__ bv,
    float* __restrict__ Qf, float* __restrict__ Kf, float* __restrict__ Vf)
{
    const int u = blockIdx.x * 256 + threadIdx.x;      // 0..65535
    if (u < 32768) {
        const int r16 = u & 15;
        const int q   = (u >> 4) & 3;
        const int rb  = (u >> 6) & 1;
        const int i   = u >> 7;                        // k-step 0..255
        const int row = rb * 16 + r16;                 // x row 0..31
        const float4* src = (const float4*)(x + (size_t)row * FIN) + (i * 8 + q * 2);
        float4 a  = src[0];
        float4 b2 = src[1];
        float wf[8] = {a.x, a.y, a.z, a.w, b2.x, b2.y, b2.z, b2.w};
        short hb[8], lb[8];
        #pragma unroll
        for (int j = 0; j < 8; ++j) {
            float hf;
            hb[j] = bf16_hi(wf[j], hf);
            lb[j] = bf16_of(wf[j] - hf);               // exact residual
        }
        bf16x8 vh = {hb[0],hb[1],hb[2],hb[3],hb[4],hb[5],hb[6],hb[7]};
        bf16x8 vl = {lb[0],lb[1],lb[2],lb[3],lb[4],lb[5],lb[6],lb[7]};
        short* dh = rb ? xh1 : xh0;
        short* dl = rb ? xl1 : xl0;
        const int ci = i * 64 + (u & 63);              // (u&63) == quad*16+r16
        ((bf16x8*)dh)[ci] = vh;
        ((bf16x8*)dl)[ci] = vl;
    }
    // bias prime: u covers [32][2048] float4 per matrix
    const int col4 = u & 2047;
    ((float4*)Qf)[u] = ((const float4*)bq)[col4];
    ((float4*)Kf)[u] = ((const float4*)bk)[col4];
    ((float4*)Vf)[u] = ((const float4*)bv)[col4];
}

// ---------------------------------------------------------------------------
// Kernel 1: fused QKV GEMM, LDS-staged W, split-K x2.
// Grid: 3 mats x 128 n-tiles(64 rows) x 2 k-chunks = 768 blocks x 256 thr
//     = exactly 3 blocks/CU (12 waves/CU), LDS 32KB/block (96KB/CU).
// Per stage: [64 rows][128 floats] via global_load_lds, 2 contiguous 512B
// runs per instruction; source XOR-preswizzled, reads XOR-swizzled.
// ---------------------------------------------------------------------------
__global__ __launch_bounds__(256) void qkv_gemm(
    const short* __restrict__ xh0, const short* __restrict__ xh1,
    const short* __restrict__ xl0, const short* __restrict__ xl1,
    const float* __restrict__ Wq, const float* __restrict__ Wk,
    const float* __restrict__ Wv,
    float* __restrict__ outQ, float* __restrict__ outK, float* __restrict__ outV)
{
    __shared__ float Ws[NT * BK];          // 64 x 128 fp32 = 32 KB

    const int tid  = threadIdx.x;
    const int wave = tid >> 6;
    const int lane = tid & 63;
    const int quad = lane >> 4;
    const int r16  = lane & 15;
    const int half = lane >> 5;            // 0/1: which row of the GLL pair
    const int l31  = lane & 31;

    const int bid   = blockIdx.x;          // 0..767
    const int which = bid >> 8;            // 0=Q 1=K 2=V
    const int rem   = bid & 255;
    const int kc    = rem >> 7;            // 0..1 k-chunk
    const int nt    = rem & 127;           // 0..127 n-tile (64 rows)

    const float* W; float* out;
    if (which == 0)      { W = Wq; out = outQ; }
    else if (which == 1) { W = Wk; out = outK; }
    else                 { W = Wv; out = outV; }

    // A fragment bases (pre-swizzled, wave-contiguous 1KB per load)
    const bf16x8* Xh0 = (const bf16x8*)xh0 + lane;
    const bf16x8* Xh1 = (const bf16x8*)xh1 + lane;
    const bf16x8* Xl0 = (const bf16x8*)xl0 + lane;
    const bf16x8* Xl1 = (const bf16x8*)xl1 + lane;

    // Staging geometry: wave stages rows [wave*16, wave*16+16) of the tile,
    // 2 rows per GLL instruction (lanes 0-31 row 2j, lanes 32-63 row 2j+1).
    // Source byte within the row's 512B window is (l31*16) ^ ((row&7)<<4)
    // so that linear LDS placement == XOR-swizzled layout.
    const size_t wrow_base = (size_t)(nt * 64 + wave * 16) * FIN + (size_t)kc * KCHUNK;

    const int   ldsrow = wave * 16 + r16;
    const char* WsB    = (const char*)Ws + ldsrow * (BK * 4);
    const int   swz    = (r16 & 7) << 4;

    f32x4 acc0 = {0.f, 0.f, 0.f, 0.f};
    f32x4 acc1 = {0.f, 0.f, 0.f, 0.f};

    #pragma unroll 1
    for (int kb = 0; kb < KCHUNK / BK; ++kb) {         // 32 stages
        // ---- stage: 8 GLL per wave, 2 rows x 512B each ----
        #pragma unroll
        for (int j = 0; j < 8; ++j) {
            const int rl   = j * 2 + half;                         // 0..15 in wave panel
            const int sbyte = (l31 * 16) ^ (((j * 2 + half) & 7) << 4);
            const float* src = W + wrow_base + (size_t)rl * FIN + kb * BK + (sbyte >> 2);
            float* dst = Ws + (wave * 16 + j * 2) * BK;            // wave-uniform
            gload_lds16(src, dst);
        }
        __syncthreads();                                           // drains vmcnt

        // ---- compute: 4 K-steps of 32 ----
        #pragma unroll
        for (int il = 0; il < 4; ++il) {
            const int i_g = kc * 128 + kb * 4 + il;                // global k-step
            bf16x8 ah0 = Xh0[i_g * 64];
            bf16x8 ah1 = Xh1[i_g * 64];
            bf16x8 al0 = Xl0[i_g * 64];
            bf16x8 al1 = Xl1[i_g * 64];

            const int koff = il * 128 + quad * 32;
            f32x4 w0 = *(const f32x4*)(WsB + ((koff     ) ^ swz));
            f32x4 w1 = *(const f32x4*)(WsB + ((koff + 16) ^ swz));

            float wf[8] = {w0[0], w0[1], w0[2], w0[3], w1[0], w1[1], w1[2], w1[3]};
            short hb[8], lb[8];
            #pragma unroll
            for (int j = 0; j < 8; ++j) {
                float hf;
                hb[j] = bf16_hi(wf[j], hf);
                lb[j] = bf16_of(wf[j] - hf);
            }
            bf16x8 wh = {hb[0],hb[1],hb[2],hb[3],hb[4],hb[5],hb[6],hb[7]};
            bf16x8 wl = {lb[0],lb[1],lb[2],lb[3],lb[4],lb[5],lb[6],lb[7]};

            acc0 = __builtin_amdgcn_mfma_f32_16x16x32_bf16(ah0, wh, acc0, 0, 0, 0);
            acc0 = __builtin_amdgcn_mfma_f32_16x16x32_bf16(al0, wh, acc0, 0, 0, 0);
            acc0 = __builtin_amdgcn_mfma_f32_16x16x32_bf16(ah0, wl, acc0, 0, 0, 0);
            acc1 = __builtin_amdgcn_mfma_f32_16x16x32_bf16(ah1, wh, acc1, 0, 0, 0);
            acc1 = __builtin_amdgcn_mfma_f32_16x16x32_bf16(al1, wh, acc1, 0, 0, 0);
            acc1 = __builtin_amdgcn_mfma_f32_16x16x32_bf16(ah1, wl, acc1, 0, 0, 0);
        }
        __syncthreads();                                           // before overwrite
    }

    // C/D layout (m89): col = lane&15, row = quad*4 + reg.
    // Output column n; atomicAdd into bias-primed out (split-K combine).
    const int n = nt * 64 + wave * 16 + r16;
    #pragma unroll
    for (int i = 0; i < 4; ++i) {
        const int m = quad * 4 + i;
        atomicAdd(&out[(size_t)m        * FOUT + n], acc0[i]);
        atomicAdd(&out[(size_t)(m + 16) * FOUT + n], acc1[i]);
    }
}

// ---------------------------------------------------------------------------
// Kernel 2: attention, fp32, single pass (no max subtraction — faithful).
// grid = 32 batches x 8 row-tiles(32) = 256 blocks, 512 thr (16 t-chunks).
// Partial buffers padded (stride 33/17) to kill 64-way LDS bank conflicts.
// ---------------------------------------------------------------------------
#define PZS 33
#define PDS 17
__global__ __launch_bounds__(512) void attention(
    const float* __restrict__ Qf, const float* __restrict__ Kf,
    const float* __restrict__ Vf, float* __restrict__ out)
{
    __shared__ float smem[16896 + 544];     // max(K|V 16384, pz 16896) + pden
    float* Ks = smem;
    float* Vs = smem + SD;

    const int b     = blockIdx.x >> 3;
    const int stile = blockIdx.x & 7;
    const int tid   = threadIdx.x;

    const float* Kb = Kf + (size_t)b * SD;
    const float* Vb = Vf + (size_t)b * SD;
    for (int i = tid; i < SD / 4; i += 512) {        // 4 iters each
        ((float4*)Ks)[i] = ((const float4*)Kb)[i];
        ((float4*)Vs)[i] = ((const float4*)Vb)[i];
    }
    __syncthreads();

    const int srow  = tid & 31;
    const int chunk = tid >> 5;             // 0..15, each covers 16 t's
    const int s     = stile * 32 + srow;

    float q[32];
    const float* Qrow = Qf + (size_t)b * SD + (size_t)s * 32;
    #pragma unroll
    for (int d = 0; d < 32; ++d) q[d] = Qrow[d];

    float z[32];
    #pragma unroll
    for (int d = 0; d < 32; ++d) z[d] = 0.f;
    float den = 0.f;

    const int t0 = chunk * 16;
    for (int t = t0; t < t0 + 16; ++t) {
        const float* krow = Ks + t * 32;
        float scr = 0.f;
        #pragma unroll
        for (int d = 0; d < 32; ++d) scr += q[d] * krow[d];
        const float e = __expf(scr);
        den += e;
        const float* vrow = Vs + t * 32;
        #pragma unroll
        for (int d = 0; d < 32; ++d) z[d] += e * vrow[d];
    }

    __syncthreads();                        // done reading Ks/Vs
    float* pz   = smem;                     // [32*16][33]
    float* pden = smem + 16896;             // [32][17]
    #pragma unroll
    for (int d = 0; d < 32; ++d) pz[(srow * 16 + chunk) * PZS + d] = z[d];
    pden[srow * PDS + chunk] = den;
    __syncthreads();

    const int row = tid >> 4;               // 0..31
    const int dq  = tid & 15;               // 0..15 -> 2 output floats
    float dsum = 0.f;
    #pragma unroll
    for (int c = 0; c < 16; ++c) dsum += pden[row * PDS + c];
    const float inv = 0.17677669529663687f / (dsum + 1e-5f);  // (1/sqrt(32))/(den+eps)

    const int so = stile * 32 + row;
    float* orow = out + (size_t)b * SD + (size_t)so * 32 + dq * 2;
    #pragma unroll
    for (int j = 0; j < 2; ++j) {
        float zz = 0.f;
        #pragma unroll
        for (int c = 0; c < 16; ++c) zz += pz[(row * 16 + c) * PZS + dq * 2 + j];
        orow[j] = zz * inv;
    }
}

// ---------------------------------------------------------------------------
extern "C" void kernel_launch(void* const* d_in, const int* in_sizes, int n_in,
                              void* d_out, int out_size, void* d_ws, size_t ws_size,
                              hipStream_t stream)
{
    const float* x  = (const float*)d_in[0];
    const float* Wq = (const float*)d_in[1];
    const float* bq = (const float*)d_in[2];
    const float* Wk = (const float*)d_in[3];
    const float* bk = (const float*)d_in[4];
    const float* Wv = (const float*)d_in[5];
    const float* bv = (const float*)d_in[6];
    float* out = (float*)d_out;

    // ws: xh0|xh1|xl0|xl1 (4 x 256KB fragment-order) | Qf | Kf | Vf  = 4 MB
    short* xh0 = (short*)d_ws;
    short* xh1 = xh0 + 131072;
    short* xl0 = xh1 + 131072;
    short* xl1 = xl0 + 131072;
    float* Qf = (float*)((char*)d_ws + (1u << 20));
    float* Kf = Qf + 262144;
    float* Vf = Kf + 262144;

    split_x_init<<<256, 256, 0, stream>>>(x, xh0, xh1, xl0, xl1,
                                          bq, bk, bv, Qf, Kf, Vf);
    qkv_gemm    <<<768, 256, 0, stream>>>(xh0, xh1, xl0, xl1,
                                          Wq, Wk, Wv, Qf, Kf, Vf);
    attention   <<<256, 512, 0, stream>>>(Qf, Kf, Vf, out);
}